// Round 9
// baseline (455.338 us; speedup 1.0000x reference)
//
#include <hip/hip_runtime.h>
#include <hip/hip_bf16.h>

// out[B,S,D_OUT] = x @ sign(W)^T + bias  ==  GEMM M=8192, N=4096, K=4096.
// Round 9: R7 + issue-before-CELL counted-lgkm. Each read batch is issued
// BEFORE the current phase's MFMA cluster (into regs dead since the previous
// CELL) and certified by a COUNTED lgkm at its consuming phase -> every batch
// drains under a 16-MFMA cluster. Staging/registers/swizzle/numerics = R7.
// Queue ledger (in-order DS retire; GL16 = vmcnt only):
//   enter ph1: 12 [a03'8 + b01'4] ; +b23(4) ; LGKM(4)  certifies a03,b01
//   enter ph2: <=4                ; +a47(8) ; LGKM(8)  certifies b23
//   enter ph3: <=8 ; vmcnt0+bar   ; +a03'(8); LGKM(8)  certifies a47  [tail: LGKM(0)]
//   enter ph4: <=8                ; +b01'(4); no wait (Q4 ops pre-certified)

#define M_DIM 8192
#define N_DIM 4096
#define K_DIM 4096
#define BM 256
#define BN 256
#define BK 64
#define NT (K_DIM / BK)  // 64

typedef __attribute__((ext_vector_type(8))) short bf16x8;
typedef __attribute__((ext_vector_type(4))) float f32x4;
typedef __attribute__((ext_vector_type(8))) unsigned short u16x8;

// ---------- conversion helpers ----------

__device__ __forceinline__ unsigned short f2bf_rne(float f) {
    unsigned u = __float_as_uint(f);
    unsigned r = (u + 0x7FFFu + ((u >> 16) & 1u)) >> 16;
    return (unsigned short)r;
}

__device__ __forceinline__ unsigned short sign_bf(float f) {
    if (f == 0.0f) return 0;
    return (unsigned short)(0x3F80u | ((__float_as_uint(f) >> 16) & 0x8000u));
}

__global__ __launch_bounds__(256) void cvt_x_kernel(
    const float* __restrict__ in, unsigned short* __restrict__ out, long nvec8) {
    long i = (long)blockIdx.x * blockDim.x + threadIdx.x;
    if (i >= nvec8) return;
    const float4* p = reinterpret_cast<const float4*>(in) + i * 2;
    float4 v0 = p[0];
    float4 v1 = p[1];
    u16x8 r;
    r[0] = f2bf_rne(v0.x); r[1] = f2bf_rne(v0.y);
    r[2] = f2bf_rne(v0.z); r[3] = f2bf_rne(v0.w);
    r[4] = f2bf_rne(v1.x); r[5] = f2bf_rne(v1.y);
    r[6] = f2bf_rne(v1.z); r[7] = f2bf_rne(v1.w);
    reinterpret_cast<u16x8*>(out)[i] = r;
}

__global__ __launch_bounds__(256) void cvt_w_kernel(
    const float* __restrict__ in, unsigned short* __restrict__ out, long nvec8) {
    long i = (long)blockIdx.x * blockDim.x + threadIdx.x;
    if (i >= nvec8) return;
    const float4* p = reinterpret_cast<const float4*>(in) + i * 2;
    float4 v0 = p[0];
    float4 v1 = p[1];
    u16x8 r;
    r[0] = sign_bf(v0.x); r[1] = sign_bf(v0.y);
    r[2] = sign_bf(v0.z); r[3] = sign_bf(v0.w);
    r[4] = sign_bf(v1.x); r[5] = sign_bf(v1.y);
    r[6] = sign_bf(v1.z); r[7] = sign_bf(v1.w);
    reinterpret_cast<u16x8*>(out)[i] = r;
}

// ---------- async global->LDS ----------

__device__ __forceinline__ void GL16(const unsigned short* g, unsigned short* l) {
    __builtin_amdgcn_global_load_lds(
        (const __attribute__((address_space(1))) unsigned int*)g,
        (__attribute__((address_space(3))) unsigned int*)l, 16, 0, 0);
}

// ---------- inline-asm ds_read_b128 with immediate byte offset ----------

template<int OFS>
__device__ __forceinline__ bf16x8 DSR(const unsigned short* p) {
    bf16x8 r;
    auto lp = (const __attribute__((address_space(3))) unsigned short*)p;
    asm volatile("ds_read_b128 %0, %1 offset:%2"
                 : "=&v"(r) : "v"(lp), "i"(OFS));
    return r;
}

#define BARRIER asm volatile("s_barrier" ::: "memory")
#define VMCNT0  asm volatile("s_waitcnt vmcnt(0)" ::: "memory")
#define LGKM(N) asm volatile("s_waitcnt lgkmcnt(" #N ")" ::: "memory")
#define SCHED0  __builtin_amdgcn_sched_barrier(0)
#define PRIO1   __builtin_amdgcn_s_setprio(1)
#define PRIO0   __builtin_amdgcn_s_setprio(0)

// 16-MFMA quadrant: 4 m-frags x 2 n-frags x 2 k-halves
#define CELL(MB, NB, Aa, Bb) \
    _Pragma("unroll") for (int m_ = 0; m_ < 4; ++m_) \
    _Pragma("unroll") for (int n_ = 0; n_ < 2; ++n_) \
    _Pragma("unroll") for (int kk_ = 0; kk_ < 2; ++kk_) \
        acc[(MB) + m_][(NB) + n_] = __builtin_amdgcn_mfma_f32_16x16x32_bf16( \
            Aa[m_][kk_], Bb[n_][kk_], acc[(MB) + m_][(NB) + n_], 0, 0, 0)

// ---------- 256x256 counted-lgkm GEMM (issue-before-CELL) ----------
// 512 thr = 8 waves (2M x 4N); wave out 128x64 = acc[8][4] f32x4.
// Per K-tile t (CUR=t&1):
//  ph1: bar | stage B23(t+1)->NXT | rd b23(t) | LGKM(4)  | Q1=a03*b01
//  ph2: bar | stage A(t+1)->NXT   | rd a47(t) | LGKM(8)  | Q2=a03*b23
//  ph3: vmcnt0 | bar | rd a03(t+1)<-NXT | LGKM(8) [tail LGKM(0)] | Q3=a47*b01
//  ph4: bar | stage B01(t+2)->CUR | rd b01(t+1)<-NXT | (no wait) | Q4=a47*b23
// Reg live-ranges (R7-proven): a03 dies Q2, b01 dies Q3, a47/b23 die Q4 ->
// each batch writes a dead set; no extra registers; no spill.

__global__ __launch_bounds__(512, 2) void gemm256f(
    const unsigned short* __restrict__ A,   // [M][K] bf16 bits
    const unsigned short* __restrict__ Bt,  // [N][K] bf16 bits (sign weights)
    const float* __restrict__ bias,         // [N]
    float* __restrict__ C)                  // [M][N] fp32
{
    __shared__ __align__(16) unsigned short As[2][BM * BK];  // 64 KiB
    __shared__ __align__(16) unsigned short Bs[2][BN * BK];  // 64 KiB

    const int tid  = threadIdx.x;
    const int lane = tid & 63;
    const int w    = tid >> 6;
    const int wr   = w >> 2;
    const int wc   = w & 3;

    // T1: XCD-aware bijective swizzle (grid = 512, divisible by 8)
    int bid = blockIdx.x;
    const int cpx = gridDim.x >> 3;
    bid = (bid & 7) * cpx + (bid >> 3);
    const int ntile = N_DIM / BN;  // 16
    const long brow = (long)(bid / ntile) * BM;
    const long bcol = (long)(bid % ntile) * BN;

    // staging lane geometry (inverse-swizzled global src, linear LDS dest)
    const int wrow8 = lane >> 3;
    const int colsw = ((lane & 7) ^ wrow8) * 8;
    const int arw_u = (w >> 2) * 128 + (w & 3) * 8;
    const int brw_u = (w >> 2) * 64 + (w & 3) * 8;
    const long aRow = brow + arw_u + wrow8;
    const long bRow = bcol + brw_u + wrow8;

#define GA(BUF, I, KT) GL16(A  + (aRow + (I) * 32) * (long)K_DIM + (colsw + (KT)), \
                            &As[BUF][(arw_u + (I) * 32) * 64])
#define GB(BUF, OFS, KT) GL16(Bt + (bRow + (OFS)) * (long)K_DIM + (colsw + (KT)), \
                              &Bs[BUF][(brw_u + (OFS)) * 64])

    // fragment read bases (swizzled), loop-invariant
    const int fr = lane & 15;
    const int fq = lane >> 4;
    const int rqu = (fq * 8) ^ ((lane & 7) << 3);
    const int aoff = (wr * 128 + fr) * 64 + rqu;
    const int boff = (wc * 64 + fr) * 64 + rqu;

    const unsigned short* As0k0 = &As[0][aoff];
    const unsigned short* As0k1 = &As[0][aoff ^ 32];
    const unsigned short* As1k0 = &As[1][aoff];
    const unsigned short* As1k1 = &As[1][aoff ^ 32];
    const unsigned short* Bs0k0 = &Bs[0][boff];
    const unsigned short* Bs0k1 = &Bs[0][boff ^ 32];
    const unsigned short* Bs1k0 = &Bs[1][boff];
    const unsigned short* Bs1k1 = &Bs[1][boff ^ 32];

    f32x4 acc[8][4];
#pragma unroll
    for (int m = 0; m < 8; ++m)
#pragma unroll
        for (int n = 0; n < 4; ++n) acc[m][n] = (f32x4){0.f, 0.f, 0.f, 0.f};

    bf16x8 a03[4][2], a47[4][2], b01[2][2], b23[2][2];

    // ----- prologue: tile0 (8 GL16 -> buf0) + tile1's B01 (2 -> buf1) -----
    GA(0, 0, 0); GA(0, 1, 0); GA(0, 2, 0); GA(0, 3, 0);
    GB(0, 0, 0); GB(0, 128, 0); GB(0, 32, 0); GB(0, 160, 0);
    GB(1, 0, BK); GB(1, 128, BK);
    VMCNT0;
    BARRIER;
    // pre-issue a03(t0) + b01(t0): 12 outstanding entering ph1 (steady-state)
    a03[0][0] = DSR<0>(As0k0);    a03[0][1] = DSR<0>(As0k1);
    a03[1][0] = DSR<2048>(As0k0); a03[1][1] = DSR<2048>(As0k1);
    a03[2][0] = DSR<4096>(As0k0); a03[2][1] = DSR<4096>(As0k1);
    a03[3][0] = DSR<6144>(As0k0); a03[3][1] = DSR<6144>(As0k1);
    b01[0][0] = DSR<0>(Bs0k0);    b01[0][1] = DSR<0>(Bs0k1);
    b01[1][0] = DSR<2048>(Bs0k0); b01[1][1] = DSR<2048>(Bs0k1);

#define TILE_BODY(TT, CUR, NXT, pAc0, pAc1, pBc0, pBc1, pAn0, pAn1, pBn0, pBn1) { \
    const long kt1 = (long)((TT) + 1) * BK; \
    const long kt2 = (long)((TT) + 2) * BK; \
    const bool s1 = ((TT) + 1 < NT); \
    const bool s2 = ((TT) + 2 < NT); \
    /* ---- ph1: rd b23(t); LGKM(4) certifies a03,b01; b23 drains under Q1 */ \
    BARRIER; \
    if (s1) { GB(NXT, 32, kt1); GB(NXT, 160, kt1); } \
    b23[0][0] = DSR<4096>(pBc0); b23[0][1] = DSR<4096>(pBc1); \
    b23[1][0] = DSR<6144>(pBc0); b23[1][1] = DSR<6144>(pBc1); \
    LGKM(4); SCHED0; \
    PRIO1; CELL(0, 0, a03, b01); PRIO0; SCHED0; \
    /* ---- ph2: rd a47(t); LGKM(8) certifies b23; a47 drains under Q2 */ \
    BARRIER; \
    if (s1) { GA(NXT, 0, kt1); GA(NXT, 1, kt1); GA(NXT, 2, kt1); GA(NXT, 3, kt1); } \
    a47[0][0] = DSR<8192>(pAc0);  a47[0][1] = DSR<8192>(pAc1); \
    a47[1][0] = DSR<10240>(pAc0); a47[1][1] = DSR<10240>(pAc1); \
    a47[2][0] = DSR<12288>(pAc0); a47[2][1] = DSR<12288>(pAc1); \
    a47[3][0] = DSR<14336>(pAc0); a47[3][1] = DSR<14336>(pAc1); \
    LGKM(8); SCHED0; \
    PRIO1; CELL(0, 2, a03, b23); PRIO0; SCHED0; \
    /* ---- ph3: drain+publish t+1 stages; rd a03(t+1); LGKM(8) certifies a47 */ \
    VMCNT0; \
    BARRIER; \
    if (s1) { \
        a03[0][0] = DSR<0>(pAn0);    a03[0][1] = DSR<0>(pAn1); \
        a03[1][0] = DSR<2048>(pAn0); a03[1][1] = DSR<2048>(pAn1); \
        a03[2][0] = DSR<4096>(pAn0); a03[2][1] = DSR<4096>(pAn1); \
        a03[3][0] = DSR<6144>(pAn0); a03[3][1] = DSR<6144>(pAn1); \
        LGKM(8); \
    } else { LGKM(0); } \
    SCHED0; \
    PRIO1; CELL(4, 0, a47, b01); PRIO0; SCHED0; \
    /* ---- ph4: rd b01(t+1); no wait (Q4 ops certified ph2/ph3) */ \
    BARRIER; \
    if (s2) { GB(CUR, 0, kt2); GB(CUR, 128, kt2); } \
    if (s1) { \
        b01[0][0] = DSR<0>(pBn0);    b01[0][1] = DSR<0>(pBn1); \
        b01[1][0] = DSR<2048>(pBn0); b01[1][1] = DSR<2048>(pBn1); \
    } \
    PRIO1; CELL(4, 2, a47, b23); PRIO0; SCHED0; \
}

    for (int t = 0; t < NT; t += 2) {
        TILE_BODY(t,     0, 1, As0k0, As0k1, Bs0k0, Bs0k1, As1k0, As1k1, Bs1k0, Bs1k1);
        TILE_BODY(t + 1, 1, 0, As1k0, As1k1, Bs1k0, Bs1k1, As0k0, As0k1, Bs0k0, Bs0k1);
    }
#undef TILE_BODY

    // ----- epilogue: C/D layout col = lane&15, row = (lane>>4)*4 + j -----
#pragma unroll
    for (int n = 0; n < 4; ++n) {
        const long cg = bcol + wc * 64 + n * 16 + fr;
        const float bv = bias[cg];
#pragma unroll
        for (int m = 0; m < 8; ++m) {
            const long rbase = brow + wr * 128 + m * 16 + fq * 4;
#pragma unroll
            for (int j = 0; j < 4; ++j)
                C[(rbase + j) * (long)N_DIM + cg] = acc[m][n][j] + bv;
        }
    }
}

// ---------- naive fallback ----------

__global__ __launch_bounds__(256) void naive_kernel(
    const float* __restrict__ x, const float* __restrict__ w,
    const float* __restrict__ bias, float* __restrict__ out, long total) {
    long gid = (long)blockIdx.x * blockDim.x + threadIdx.x;
    if (gid >= total) return;
    long m = gid / N_DIM, n = gid % N_DIM;
    const float* xr = x + m * (long)K_DIM;
    const float* wr = w + n * (long)K_DIM;
    float s = 0.f;
    for (int k = 0; k < K_DIM; ++k) {
        float wv = wr[k];
        float sg = (wv > 0.f) ? 1.f : ((wv < 0.f) ? -1.f : 0.f);
        s += xr[k] * sg;
    }
    out[gid] = s + bias[n];
}

// ---------- launch ----------

extern "C" void kernel_launch(void* const* d_in, const int* in_sizes, int n_in,
                              void* d_out, int out_size, void* d_ws, size_t ws_size,
                              hipStream_t stream) {
    const float* x    = (const float*)d_in[0];
    const float* w    = (const float*)d_in[1];
    const float* bias = (const float*)d_in[2];
    float* out = (float*)d_out;

    const size_t nA = (size_t)M_DIM * K_DIM;
    const size_t nB = (size_t)N_DIM * K_DIM;
    const size_t need_bytes = (nA + nB) * sizeof(unsigned short);

    if (ws_size >= need_bytes) {
        unsigned short* xb = (unsigned short*)d_ws;
        unsigned short* wb = xb + nA;
        {
            long nvec8 = (long)(nA / 8);
            cvt_x_kernel<<<(int)((nvec8 + 255) / 256), 256, 0, stream>>>(x, xb, nvec8);
        }
        {
            long nvec8 = (long)(nB / 8);
            cvt_w_kernel<<<(int)((nvec8 + 255) / 256), 256, 0, stream>>>(w, wb, nvec8);
        }
        dim3 grid((M_DIM / BM) * (N_DIM / BN));  // 512
        gemm256f<<<grid, 512, 0, stream>>>(xb, wb, bias, out);
    } else {
        long total = (long)M_DIM * N_DIM;
        naive_kernel<<<(int)((total + 255) / 256), 256, 0, stream>>>(x, w, bias, out, total);
    }
}

// Round 10
// 269.684 us; speedup vs baseline: 1.6884x; 1.6884x over previous
//
#include <hip/hip_runtime.h>
#include <hip/hip_bf16.h>

// out[B,S,D_OUT] = x @ sign(W)^T + bias  ==  GEMM M=8192, N=4096, K=4096.
// Round 10: R7 (best, 276us GEMM) + counted vmcnt ONLY (T4). R7's read/lgkm
// structure untouched (R8/R9 showed changing it regresses). ph3: vmcnt(0) ->
// vmcnt(6) (confirms B01[t+1], staged 3 phases back; leaves B23/A[t+1] in
// flight). End of ph4: new vmcnt(2) (confirms B23+A[t+1] before ph1(t+1)'s
// a03 DSRs; leaves B01[t+2] in flight). Tail uses vmcnt(0). HBM latency of
// the youngest stage is no longer exposed at any wait.

#define M_DIM 8192
#define N_DIM 4096
#define K_DIM 4096
#define BM 256
#define BN 256
#define BK 64
#define NT (K_DIM / BK)  // 64

typedef __attribute__((ext_vector_type(8))) short bf16x8;
typedef __attribute__((ext_vector_type(4))) float f32x4;
typedef __attribute__((ext_vector_type(8))) unsigned short u16x8;

// ---------- conversion helpers ----------

__device__ __forceinline__ unsigned short f2bf_rne(float f) {
    unsigned u = __float_as_uint(f);
    unsigned r = (u + 0x7FFFu + ((u >> 16) & 1u)) >> 16;
    return (unsigned short)r;
}

__device__ __forceinline__ unsigned short sign_bf(float f) {
    if (f == 0.0f) return 0;
    return (unsigned short)(0x3F80u | ((__float_as_uint(f) >> 16) & 0x8000u));
}

__global__ __launch_bounds__(256) void cvt_x_kernel(
    const float* __restrict__ in, unsigned short* __restrict__ out, long nvec8) {
    long i = (long)blockIdx.x * blockDim.x + threadIdx.x;
    if (i >= nvec8) return;
    const float4* p = reinterpret_cast<const float4*>(in) + i * 2;
    float4 v0 = p[0];
    float4 v1 = p[1];
    u16x8 r;
    r[0] = f2bf_rne(v0.x); r[1] = f2bf_rne(v0.y);
    r[2] = f2bf_rne(v0.z); r[3] = f2bf_rne(v0.w);
    r[4] = f2bf_rne(v1.x); r[5] = f2bf_rne(v1.y);
    r[6] = f2bf_rne(v1.z); r[7] = f2bf_rne(v1.w);
    reinterpret_cast<u16x8*>(out)[i] = r;
}

__global__ __launch_bounds__(256) void cvt_w_kernel(
    const float* __restrict__ in, unsigned short* __restrict__ out, long nvec8) {
    long i = (long)blockIdx.x * blockDim.x + threadIdx.x;
    if (i >= nvec8) return;
    const float4* p = reinterpret_cast<const float4*>(in) + i * 2;
    float4 v0 = p[0];
    float4 v1 = p[1];
    u16x8 r;
    r[0] = sign_bf(v0.x); r[1] = sign_bf(v0.y);
    r[2] = sign_bf(v0.z); r[3] = sign_bf(v0.w);
    r[4] = sign_bf(v1.x); r[5] = sign_bf(v1.y);
    r[6] = sign_bf(v1.z); r[7] = sign_bf(v1.w);
    reinterpret_cast<u16x8*>(out)[i] = r;
}

// ---------- async global->LDS ----------

__device__ __forceinline__ void GL16(const unsigned short* g, unsigned short* l) {
    __builtin_amdgcn_global_load_lds(
        (const __attribute__((address_space(1))) unsigned int*)g,
        (__attribute__((address_space(3))) unsigned int*)l, 16, 0, 0);
}

// ---------- inline-asm ds_read_b128 with immediate byte offset ----------

template<int OFS>
__device__ __forceinline__ bf16x8 DSR(const unsigned short* p) {
    bf16x8 r;
    auto lp = (const __attribute__((address_space(3))) unsigned short*)p;
    asm volatile("ds_read_b128 %0, %1 offset:%2"
                 : "=&v"(r) : "v"(lp), "i"(OFS));
    return r;
}

#define BARRIER asm volatile("s_barrier" ::: "memory")
#define VMCNT0  asm volatile("s_waitcnt vmcnt(0)" ::: "memory")
#define VMCNT2  asm volatile("s_waitcnt vmcnt(2)" ::: "memory")
#define VMCNT6  asm volatile("s_waitcnt vmcnt(6)" ::: "memory")
#define LGKM0   asm volatile("s_waitcnt lgkmcnt(0)" ::: "memory")
#define SCHED0  __builtin_amdgcn_sched_barrier(0)
#define PRIO1   __builtin_amdgcn_s_setprio(1)
#define PRIO0   __builtin_amdgcn_s_setprio(0)

// 16-MFMA quadrant: 4 m-frags x 2 n-frags x 2 k-halves
#define CELL(MB, NB, Aa, Bb) \
    _Pragma("unroll") for (int m_ = 0; m_ < 4; ++m_) \
    _Pragma("unroll") for (int n_ = 0; n_ < 2; ++n_) \
    _Pragma("unroll") for (int kk_ = 0; kk_ < 2; ++kk_) \
        acc[(MB) + m_][(NB) + n_] = __builtin_amdgcn_mfma_f32_16x16x32_bf16( \
            Aa[m_][kk_], Bb[n_][kk_], acc[(MB) + m_][(NB) + n_], 0, 0, 0)

// ---------- 256x256 4-phase GEMM (R7 schedule) + counted vmcnt ----------
// 512 thr = 8 waves (2M x 4N); wave out 128x64 = acc[8][4] f32x4.
// Per K-tile t (CUR=t&1):
//  ph1: bar | stage B23(t+1)->NXT | rd a03(t) | lgkm0 | Q1=a03*b01 | rd b23(t)
//  ph2: bar | stage A(t+1)->NXT               | lgkm0 | Q2=a03*b23 | rd a47(t)
//  ph3: vmcnt(6) [confirms B01(t+1), staged ph4(t-1)] | bar | lgkm0
//       | Q3=a47*b01 | rd b01(t+1)<-NXT
//  ph4: bar | stage B01(t+2)->CUR | Q4=a47*b23
//       | vmcnt(s2?2:0) [confirms B23+A(t+1); leaves B01(t+2) in flight]
// vmcnt ledger (in-order retire): at ph3(t): outstanding = B01[t+1](2)+
// B23[t+1](2)+A[t+1](4) = 8 -> vmcnt(6) drains oldest 2 = B01[t+1].
// At ph4(t) end: outstanding = B23[t+1](2)+A[t+1](4)+B01[t+2](2) = 8 ->
// vmcnt(2) drains oldest 6 = B23+A[t+1], needed by ph1(t+1)'s reads.
// Tail t=NT-2: B01[NT] not staged -> vmcnt(0). All publication (wait before
// barrier, read after) and stage-after-read windows identical to R7.

__global__ __launch_bounds__(512, 2) void gemm256g(
    const unsigned short* __restrict__ A,   // [M][K] bf16 bits
    const unsigned short* __restrict__ Bt,  // [N][K] bf16 bits (sign weights)
    const float* __restrict__ bias,         // [N]
    float* __restrict__ C)                  // [M][N] fp32
{
    __shared__ __align__(16) unsigned short As[2][BM * BK];  // 64 KiB
    __shared__ __align__(16) unsigned short Bs[2][BN * BK];  // 64 KiB

    const int tid  = threadIdx.x;
    const int lane = tid & 63;
    const int w    = tid >> 6;
    const int wr   = w >> 2;
    const int wc   = w & 3;

    // T1: XCD-aware bijective swizzle (grid = 512, divisible by 8)
    int bid = blockIdx.x;
    const int cpx = gridDim.x >> 3;
    bid = (bid & 7) * cpx + (bid >> 3);
    const int ntile = N_DIM / BN;  // 16
    const long brow = (long)(bid / ntile) * BM;
    const long bcol = (long)(bid % ntile) * BN;

    // staging lane geometry (inverse-swizzled global src, linear LDS dest)
    const int wrow8 = lane >> 3;
    const int colsw = ((lane & 7) ^ wrow8) * 8;
    const int arw_u = (w >> 2) * 128 + (w & 3) * 8;
    const int brw_u = (w >> 2) * 64 + (w & 3) * 8;
    const long aRow = brow + arw_u + wrow8;
    const long bRow = bcol + brw_u + wrow8;

#define GA(BUF, I, KT) GL16(A  + (aRow + (I) * 32) * (long)K_DIM + (colsw + (KT)), \
                            &As[BUF][(arw_u + (I) * 32) * 64])
#define GB(BUF, OFS, KT) GL16(Bt + (bRow + (OFS)) * (long)K_DIM + (colsw + (KT)), \
                              &Bs[BUF][(brw_u + (OFS)) * 64])

    // fragment read bases (swizzled), loop-invariant
    const int fr = lane & 15;
    const int fq = lane >> 4;
    const int rqu = (fq * 8) ^ ((lane & 7) << 3);
    const int aoff = (wr * 128 + fr) * 64 + rqu;
    const int boff = (wc * 64 + fr) * 64 + rqu;

    const unsigned short* As0k0 = &As[0][aoff];
    const unsigned short* As0k1 = &As[0][aoff ^ 32];
    const unsigned short* As1k0 = &As[1][aoff];
    const unsigned short* As1k1 = &As[1][aoff ^ 32];
    const unsigned short* Bs0k0 = &Bs[0][boff];
    const unsigned short* Bs0k1 = &Bs[0][boff ^ 32];
    const unsigned short* Bs1k0 = &Bs[1][boff];
    const unsigned short* Bs1k1 = &Bs[1][boff ^ 32];

    f32x4 acc[8][4];
#pragma unroll
    for (int m = 0; m < 8; ++m)
#pragma unroll
        for (int n = 0; n < 4; ++n) acc[m][n] = (f32x4){0.f, 0.f, 0.f, 0.f};

    bf16x8 a03[4][2], a47[4][2], b01[2][2], b23[2][2];

    // ----- prologue: tile0 (8 GL16 -> buf0) + tile1's B01 (2 -> buf1) -----
    GA(0, 0, 0); GA(0, 1, 0); GA(0, 2, 0); GA(0, 3, 0);
    GB(0, 0, 0); GB(0, 128, 0); GB(0, 32, 0); GB(0, 160, 0);
    GB(1, 0, BK); GB(1, 128, BK);
    VMCNT0;
    BARRIER;
    // pre-issue b01(t=0); certified at ph1(0)'s lgkm0
    b01[0][0] = DSR<0>(Bs0k0);    b01[0][1] = DSR<0>(Bs0k1);
    b01[1][0] = DSR<2048>(Bs0k0); b01[1][1] = DSR<2048>(Bs0k1);

#define TILE_BODY(TT, CUR, NXT, pAc0, pAc1, pBc0, pBc1, pBn0, pBn1) { \
    const long kt1 = (long)((TT) + 1) * BK; \
    const long kt2 = (long)((TT) + 2) * BK; \
    const bool s1 = ((TT) + 1 < NT); \
    const bool s2 = ((TT) + 2 < NT); \
    /* ---- ph1 ---- */ \
    BARRIER; \
    if (s1) { GB(NXT, 32, kt1); GB(NXT, 160, kt1); } \
    a03[0][0] = DSR<0>(pAc0);    a03[0][1] = DSR<0>(pAc1); \
    a03[1][0] = DSR<2048>(pAc0); a03[1][1] = DSR<2048>(pAc1); \
    a03[2][0] = DSR<4096>(pAc0); a03[2][1] = DSR<4096>(pAc1); \
    a03[3][0] = DSR<6144>(pAc0); a03[3][1] = DSR<6144>(pAc1); \
    LGKM0; SCHED0; \
    PRIO1; CELL(0, 0, a03, b01); PRIO0; SCHED0; \
    b23[0][0] = DSR<4096>(pBc0); b23[0][1] = DSR<4096>(pBc1); \
    b23[1][0] = DSR<6144>(pBc0); b23[1][1] = DSR<6144>(pBc1); \
    /* ---- ph2 ---- */ \
    BARRIER; \
    if (s1) { GA(NXT, 0, kt1); GA(NXT, 1, kt1); GA(NXT, 2, kt1); GA(NXT, 3, kt1); } \
    LGKM0; SCHED0; \
    PRIO1; CELL(0, 2, a03, b23); PRIO0; SCHED0; \
    a47[0][0] = DSR<8192>(pAc0);  a47[0][1] = DSR<8192>(pAc1); \
    a47[1][0] = DSR<10240>(pAc0); a47[1][1] = DSR<10240>(pAc1); \
    a47[2][0] = DSR<12288>(pAc0); a47[2][1] = DSR<12288>(pAc1); \
    a47[3][0] = DSR<14336>(pAc0); a47[3][1] = DSR<14336>(pAc1); \
    /* ---- ph3: counted drain (B01[t+1] confirmed; B23/A[t+1] in flight) ---- */ \
    VMCNT6; \
    BARRIER; \
    LGKM0; SCHED0; \
    PRIO1; CELL(4, 0, a47, b01); PRIO0; SCHED0; \
    if (s1) { \
        b01[0][0] = DSR<0>(pBn0);    b01[0][1] = DSR<0>(pBn1); \
        b01[1][0] = DSR<2048>(pBn0); b01[1][1] = DSR<2048>(pBn1); \
    } \
    /* ---- ph4 ---- */ \
    BARRIER; \
    if (s2) { GB(CUR, 0, kt2); GB(CUR, 128, kt2); } \
    PRIO1; CELL(4, 2, a47, b23); PRIO0; SCHED0; \
    /* confirm B23+A[t+1] for ph1(t+1); leave B01[t+2] in flight */ \
    if (s2) { VMCNT2; } else { VMCNT0; } \
}

    for (int t = 0; t < NT; t += 2) {
        TILE_BODY(t,     0, 1, As0k0, As0k1, Bs0k0, Bs0k1, Bs1k0, Bs1k1);
        TILE_BODY(t + 1, 1, 0, As1k0, As1k1, Bs1k0, Bs1k1, Bs0k0, Bs0k1);
    }
#undef TILE_BODY

    // ----- epilogue: C/D layout col = lane&15, row = (lane>>4)*4 + j -----
#pragma unroll
    for (int n = 0; n < 4; ++n) {
        const long cg = bcol + wc * 64 + n * 16 + fr;
        const float bv = bias[cg];
#pragma unroll
        for (int m = 0; m < 8; ++m) {
            const long rbase = brow + wr * 128 + m * 16 + fq * 4;
#pragma unroll
            for (int j = 0; j < 4; ++j)
                C[(rbase + j) * (long)N_DIM + cg] = acc[m][n][j] + bv;
        }
    }
}

// ---------- naive fallback ----------

__global__ __launch_bounds__(256) void naive_kernel(
    const float* __restrict__ x, const float* __restrict__ w,
    const float* __restrict__ bias, float* __restrict__ out, long total) {
    long gid = (long)blockIdx.x * blockDim.x + threadIdx.x;
    if (gid >= total) return;
    long m = gid / N_DIM, n = gid % N_DIM;
    const float* xr = x + m * (long)K_DIM;
    const float* wr = w + n * (long)K_DIM;
    float s = 0.f;
    for (int k = 0; k < K_DIM; ++k) {
        float wv = wr[k];
        float sg = (wv > 0.f) ? 1.f : ((wv < 0.f) ? -1.f : 0.f);
        s += xr[k] * sg;
    }
    out[gid] = s + bias[n];
}

// ---------- launch ----------

extern "C" void kernel_launch(void* const* d_in, const int* in_sizes, int n_in,
                              void* d_out, int out_size, void* d_ws, size_t ws_size,
                              hipStream_t stream) {
    const float* x    = (const float*)d_in[0];
    const float* w    = (const float*)d_in[1];
    const float* bias = (const float*)d_in[2];
    float* out = (float*)d_out;

    const size_t nA = (size_t)M_DIM * K_DIM;
    const size_t nB = (size_t)N_DIM * K_DIM;
    const size_t need_bytes = (nA + nB) * sizeof(unsigned short);

    if (ws_size >= need_bytes) {
        unsigned short* xb = (unsigned short*)d_ws;
        unsigned short* wb = xb + nA;
        {
            long nvec8 = (long)(nA / 8);
            cvt_x_kernel<<<(int)((nvec8 + 255) / 256), 256, 0, stream>>>(x, xb, nvec8);
        }
        {
            long nvec8 = (long)(nB / 8);
            cvt_w_kernel<<<(int)((nvec8 + 255) / 256), 256, 0, stream>>>(w, wb, nvec8);
        }
        dim3 grid((M_DIM / BM) * (N_DIM / BN));  // 512
        gemm256g<<<grid, 512, 0, stream>>>(xb, wb, bias, out);
    } else {
        long total = (long)M_DIM * N_DIM;
        naive_kernel<<<(int)((total + 255) / 256), 256, 0, stream>>>(x, w, bias, out, total);
    }
}